// Round 6
// baseline (83.110 us; speedup 1.0000x reference)
//
#include <hip/hip_runtime.h>

#define NROWS 8192
#define KD    128
#define SQK1C 4.5398163f   /* sqrt(log2(e)/0.07); scaled ops make MFMA emit K1C*sim */

typedef __bf16 bf16x8 __attribute__((ext_vector_type(8)));
typedef float  f32x4  __attribute__((ext_vector_type(4)));

typedef __attribute__((address_space(1))) void* gas_ptr;
typedef __attribute__((address_space(3))) void* las_ptr;

__device__ __forceinline__ unsigned short f2bf(float x) {
  unsigned int u = __builtin_bit_cast(unsigned int, x);
  unsigned int r = (u + 0x7FFFu + ((u >> 16) & 1u)) >> 16;  // RNE
  return (unsigned short)r;
}

// fp32 -> bf16 scaled by sqrt(K1C); zero the 4 sum arrays.
__global__ __launch_bounds__(256) void prep_kernel(const float4* __restrict__ F4,
                                                   const float4* __restrict__ M4,
                                                   ushort4* __restrict__ Fb4,
                                                   ushort4* __restrict__ Mb4,
                                                   float* __restrict__ sums) {
  int i = blockIdx.x * 256 + threadIdx.x;
  float4 f = F4[i];
  float4 m = M4[i];
  ushort4 fo, mo;
  fo.x = f2bf(f.x * SQK1C); fo.y = f2bf(f.y * SQK1C);
  fo.z = f2bf(f.z * SQK1C); fo.w = f2bf(f.w * SQK1C);
  mo.x = f2bf(m.x * SQK1C); mo.y = f2bf(m.y * SQK1C);
  mo.z = f2bf(m.z * SQK1C); mo.w = f2bf(m.w * SQK1C);
  Fb4[i] = fo;
  Mb4[i] = mo;
  if (i < 4 * NROWS) sums[i] = 0.0f;
}

// z=0: FM full (rowsum->Spos_f, colsum->Spos_m).
// z=1/2: FF/MM UPPER TRIANGLE only (symmetric): below-diag chunks prefix-skipped;
//   diagonal-zone chunks (C in [R, R+128)) full compute, diag-masked, rowsum only;
//   above-diag chunks (C >= R+128) dual: rowsum[row] + mirror atomic into rowsum[col].
// 4 waves (2 wr x 2 wc). Strip 128 rows x 1024 cols; 16 chunks of 64 cols.
// A in regs (af -> AGPR side of unified file); B double-buffered 2x16KB LDS.
__global__ __launch_bounds__(256, 3) void gemm_kernel(const unsigned short* __restrict__ Fb,
                                                      const unsigned short* __restrict__ Mb,
                                                      float* __restrict__ sums) {
  __shared__ __align__(16) unsigned short lds[2][64 * KD];  // 2 x 16KB (A-stage borrows 32KB)

  const int bx = blockIdx.x;   // 0..7   col strip (1024)
  const int by = blockIdx.y;   // 0..63  row block (128)
  const int z  = blockIdx.z;   // 0..2
  const int R  = by * 128;

  // prefix-skip for triangle (chunks below diagonal): chunk t covers cols [bx*1024+t*64, +64)
  int t0 = 0;
  if (z > 0) {
    const int d = R - bx * 1024;
    t0 = (d <= 0) ? 0 : (d >> 6);
    if (t0 >= 16) return;               // whole strip strictly below diagonal
  }

  const unsigned short* A;
  const unsigned short* B;
  float* rowsum;
  float* colsum = nullptr;
  if (z == 0)      { A = Fb; B = Mb; rowsum = sums;             colsum = sums + NROWS; }
  else if (z == 1) { A = Fb; B = Fb; rowsum = sums + 2 * NROWS; }
  else             { A = Mb; B = Mb; rowsum = sums + 3 * NROWS; }
  // mirror target for sym dual chunks is the rowsum array itself
  float* cbase = (z == 0) ? colsum : rowsum;

  const int tid  = threadIdx.x;
  const int lane = tid & 63;
  const int wave = tid >> 6;          // 0..3
  const int wr = wave >> 1, wc = wave & 1;
  const int l15 = lane & 15, l4 = lane >> 4;

  // Stage one 16KB B-chunk (64 rows x 256B). Linear LDS dest; source pre-XORed (rule 21).
  auto stageB = [&](void* dst, const unsigned short* src) {
    #pragma unroll
    for (int i = 0; i < 4; ++i) {
      const int lin = tid * 16 + i * 4096;
      const int row = lin >> 8;
      const int sbc = (lin & 255) ^ ((row & 7) << 4);
      __builtin_amdgcn_global_load_lds((gas_ptr)((const char*)src + row * 256 + sbc),
                                       (las_ptr)((char*)dst + lin), 16, 0, 0);
    }
  };

  // ---- A strip (32KB) through LDS into regs
  {
    const unsigned short* Abase = A + (size_t)by * 128 * KD;
    #pragma unroll
    for (int i = 0; i < 8; ++i) {
      const int lin = tid * 16 + i * 4096;
      const int row = lin >> 8;
      const int sbc = (lin & 255) ^ ((row & 7) << 4);
      __builtin_amdgcn_global_load_lds((gas_ptr)((const char*)Abase + row * 256 + sbc),
                                       (las_ptr)((char*)lds + lin), 16, 0, 0);
    }
  }
  __syncthreads();

  bf16x8 af[4][4];   // 64 rows x K128 per wave
  #pragma unroll
  for (int m = 0; m < 4; ++m) {
    const int row = wr * 64 + m * 16 + l15;
    const char* ab = (const char*)lds + row * 256;
    const int sw = (row & 7) << 4;
    #pragma unroll
    for (int k = 0; k < 4; ++k)
      af[m][k] = *(const bf16x8*)(ab + ((k * 64 + l4 * 16) ^ sw));
  }
  __syncthreads();   // all waves done with A before B chunk t0 overwrites

  float rowacc[16];
  #pragma unroll
  for (int i = 0; i < 16; ++i) rowacc[i] = 0.f;

  const unsigned short* Bbase = B + (size_t)bx * 1024 * KD;
  stageB(lds[t0 & 1], Bbase + (size_t)t0 * 64 * KD);
  if (t0 + 1 < 16) stageB(lds[(t0 + 1) & 1], Bbase + (size_t)(t0 + 1) * 64 * KD);
  __syncthreads();

  const int brow0 = wc * 32 + l15;          // n=0 B-row (out col); n=1 adds 16
  const int bsw   = (brow0 & 7) << 4;       // (brow0+16)&7 == brow0&7

  for (int t = t0; t < 16; ++t) {
    const char* bb = (const char*)lds[t & 1];
    const char* pb0 = bb + brow0 * 256;

    f32x4 acc[4][2] = {};
    __builtin_amdgcn_s_setprio(1);
    #pragma unroll
    for (int k = 0; k < 4; ++k) {
      const int c = (k * 64 + l4 * 16) ^ bsw;
      bf16x8 b0 = *(const bf16x8*)(pb0 + c);
      bf16x8 b1 = *(const bf16x8*)(pb0 + 16 * 256 + c);
      #pragma unroll
      for (int m = 0; m < 4; ++m) {
        acc[m][0] = __builtin_amdgcn_mfma_f32_16x16x32_bf16(af[m][k], b0, acc[m][0], 0, 0, 0);
        acc[m][1] = __builtin_amdgcn_mfma_f32_16x16x32_bf16(af[m][k], b1, acc[m][1], 0, 0, 0);
      }
    }
    __builtin_amdgcn_s_setprio(0);

    // Epilogue: v = exp2(K1C*sim).
    const int  C    = bx * 1024 + t * 64;            // chunk col base
    const bool dual = (z == 0) || (C >= R + 128);    // needs col accumulation
    if (dual) {
      float ca0 = 0.f, ca1 = 0.f;
      #pragma unroll
      for (int m = 0; m < 4; ++m) {
        #pragma unroll
        for (int j = 0; j < 4; ++j) {
          float v0 = __builtin_amdgcn_exp2f(acc[m][0][j]);
          float v1 = __builtin_amdgcn_exp2f(acc[m][1][j]);
          rowacc[m * 4 + j] += v0 + v1;
          ca0 += v0; ca1 += v1;
        }
      }
      ca0 += __shfl_xor(ca0, 16);
      ca0 += __shfl_xor(ca0, 32);
      ca1 += __shfl_xor(ca1, 16);
      ca1 += __shfl_xor(ca1, 32);
      if (l4 == 0) {
        float* cp = cbase + C + wc * 32 + l15;
        unsafeAtomicAdd(cp, ca0);
        unsafeAtomicAdd(cp + 16, ca1);
      }
    } else {
      // diagonal-zone chunk of a symmetric GEMM: mask self-sim, rowsum only
      #pragma unroll
      for (int m = 0; m < 4; ++m) {
        #pragma unroll
        for (int j = 0; j < 4; ++j) {
          float v0 = __builtin_amdgcn_exp2f(acc[m][0][j]);
          float v1 = __builtin_amdgcn_exp2f(acc[m][1][j]);
          const int grow = R + wr * 64 + m * 16 + l4 * 4 + j;
          const int gcol = C + wc * 32 + l15;
          if (grow == gcol)      v0 = 0.f;
          if (grow == gcol + 16) v1 = 0.f;
          rowacc[m * 4 + j] += v0 + v1;
        }
      }
    }
    __syncthreads();                    // drains vmcnt+lgkm; buffer t&1 free to re-stage
    if (t + 2 < 16) stageB(lds[t & 1], Bbase + (size_t)(t + 2) * 64 * KD);
  }

  // rowsum flush: butterfly over l15 (cols), 4 lanes/wave do the atomics.
  #pragma unroll
  for (int i = 0; i < 16; ++i) {
    float v = rowacc[i];
    v += __shfl_xor(v, 1);
    v += __shfl_xor(v, 2);
    v += __shfl_xor(v, 4);
    v += __shfl_xor(v, 8);
    rowacc[i] = v;
  }
  if (l15 == 0) {
    const int rbase = R + wr * 64 + l4 * 4;
    #pragma unroll
    for (int i = 0; i < 16; ++i)
      unsafeAtomicAdd(rowsum + rbase + (i >> 2) * 16 + (i & 3), rowacc[i]);
  }
}

// loss = 1.5*mean(log1p(Sneg_f/Spos_f)) + 0.5*mean(log1p(Sneg_m/Spos_m))
// (uniform 2^{-K1C} factor cancels in the ratios)
__global__ __launch_bounds__(1024) void loss_kernel(const float* __restrict__ sums,
                                                    float* __restrict__ out) {
  const float* Spf = sums;
  const float* Spm = sums + NROWS;
  const float* Snf = sums + 2 * NROWS;
  const float* Snm = sums + 3 * NROWS;
  float accf = 0.f, accm = 0.f;
  for (int i = threadIdx.x; i < NROWS; i += 1024) {
    accf += log1pf(Snf[i] / Spf[i]);
    accm += log1pf(Snm[i] / Spm[i]);
  }
  float v = 1.5f * accf + 0.5f * accm;
  #pragma unroll
  for (int s = 1; s < 64; s <<= 1) v += __shfl_xor(v, s);
  __shared__ float red[16];
  if ((threadIdx.x & 63) == 0) red[threadIdx.x >> 6] = v;
  __syncthreads();
  if (threadIdx.x == 0) {
    float s = 0.f;
    #pragma unroll
    for (int i = 0; i < 16; ++i) s += red[i];
    out[0] = s * (1.0f / NROWS);
  }
}

extern "C" void kernel_launch(void* const* d_in, const int* in_sizes, int n_in,
                              void* d_out, int out_size, void* d_ws, size_t ws_size,
                              hipStream_t stream) {
  (void)in_sizes; (void)n_in; (void)out_size; (void)ws_size;
  const float* F = (const float*)d_in[0];
  const float* M = (const float*)d_in[1];
  float* out = (float*)d_out;

  float* sums = (float*)d_ws;
  unsigned short* Fb = (unsigned short*)((char*)d_ws + 4 * NROWS * sizeof(float));
  unsigned short* Mb = Fb + (size_t)NROWS * KD;

  prep_kernel<<<dim3(NROWS * KD / 4 / 256), dim3(256), 0, stream>>>(
      (const float4*)F, (const float4*)M, (ushort4*)Fb, (ushort4*)Mb, sums);
  gemm_kernel<<<dim3(8, 64, 3), dim3(256), 0, stream>>>(Fb, Mb, sums);
  loss_kernel<<<dim3(1), dim3(1024), 0, stream>>>(sums, out);
}